// Round 9
// baseline (4305.861 us; speedup 1.0000x reference)
//
#include <hip/hip_runtime.h>
#include <hip/hip_bf16.h>
#include <cstdint>
#include <cstddef>

// ---------------------------------------------------------------------------
// TimeAwareFeatViT forward, MI355X (gfx950).
// R8: R7 + BK-templated GEMM. Measured (R8 counters): N=768 GEMMs are
// stall-bound in the 2-barrier K-loop (Occ 29.5% yet MfmaUtil 18%, HBM 12.7%).
// Fix: TM=64 + BK=128 for N=768 GEMMs + embedding -> half the vmcnt(0)+barrier
// drains per K at unchanged 3 blocks/CU (LDS 48KB*3=144 < 160KB). qkv/mlp1
// keep TM=128/BK=64 (grid already 4.5-6 blocks/CU).
// ---------------------------------------------------------------------------

typedef __attribute__((ext_vector_type(8))) short bf16x8;  // 8 bf16 = 4 VGPRs
typedef __attribute__((ext_vector_type(4))) short s16x4;
typedef __attribute__((ext_vector_type(4))) float f32x4;

#define DEVFN __device__ __forceinline__

constexpr int BATCH = 16, SEQ = 512, FDIM = 1024, DIM = 768, NLAYER = 12;
constexpr int NH = 12, DHEAD = 64, DMLP = 3072;
constexpr int TOK = BATCH * SEQ;      // 8192
constexpr int QKVN = 3 * DIM;         // 2304

DEVFN short f2bf(float f) {           // fp32 -> bf16 bits, RNE
    union { float f; uint32_t u; } v; v.f = f;
    uint32_t r = v.u + 0x7FFFu + ((v.u >> 16) & 1u);
    return (short)(r >> 16);
}

DEVFN f32x4 mfma16(bf16x8 a, bf16x8 b, f32x4 c) {
    return __builtin_amdgcn_mfma_f32_16x16x32_bf16(a, b, c, 0, 0, 0);
}

// jax.nn.gelu approximate=True: 0.5x(1+tanh(c(x+0.044715x^3))) == x*sigmoid(2c(x+0.044715x^3))
DEVFN float gelu_tanh(float x) {
    const float c2 = 1.5957691216057308f;   // 2*sqrt(2/pi)
    float u = c2 * (x + 0.044715f * x * x * x);
    return x / (1.0f + __expf(-u));
}

// async global->LDS, 16B per lane; lds base must be wave-uniform
#define GLOAD_LDS16(gp, lp)                                                     \
    __builtin_amdgcn_global_load_lds(                                           \
        (const __attribute__((address_space(1))) void*)(gp),                    \
        (__attribute__((address_space(3))) void*)(lp), 16, 0, 0)

// ---------------------------------------------------------------------------
// fp32 -> bf16 elementwise convert (vectorized, grid-stride) — for feat
// ---------------------------------------------------------------------------
__global__ void cvt_f32_bf16(const float* __restrict__ in, short* __restrict__ out, int n4) {
    int i = blockIdx.x * blockDim.x + threadIdx.x;
    int stride = gridDim.x * blockDim.x;
    for (; i < n4; i += stride) {
        f32x4 v = reinterpret_cast<const f32x4*>(in)[i];
        s16x4 o;
        o[0] = f2bf(v[0]); o[1] = f2bf(v[1]); o[2] = f2bf(v[2]); o[3] = f2bf(v[3]);
        reinterpret_cast<s16x4*>(out)[i] = o;
    }
}

// ---------------------------------------------------------------------------
// Transpose + convert: in [L][K][N] f32 -> out [L][N][K] bf16. 64x64 LDS tile,
// both sides coalesced. Grid (K/64, N/64, L), 256 threads.
// ---------------------------------------------------------------------------
__global__ __launch_bounds__(256)
void transpose_cvt(const float* __restrict__ in, short* __restrict__ out, int K, int N) {
    __shared__ float tile[64][65];
    const size_t lo = (size_t)blockIdx.z * K * N;
    const float* src = in + lo;
    short* dst = out + lo;
    const int k0 = blockIdx.x * 64, n0 = blockIdx.y * 64;
    const int tid = threadIdx.x;
#pragma unroll
    for (int p = 0; p < 4; ++p) {                      // read 16 k-rows / pass
        int r = p * 16 + (tid >> 4);
        int c = (tid & 15) * 4;
        f32x4 v = *reinterpret_cast<const f32x4*>(&src[(size_t)(k0 + r) * N + n0 + c]);
        tile[r][c] = v[0]; tile[r][c + 1] = v[1]; tile[r][c + 2] = v[2]; tile[r][c + 3] = v[3];
    }
    __syncthreads();
#pragma unroll
    for (int p = 0; p < 2; ++p) {                      // write 32 n-rows / pass
        int n = p * 32 + (tid >> 3);
        int kk = (tid & 7) * 8;
        union { uint4 v; short s[8]; } o;
#pragma unroll
        for (int j = 0; j < 8; ++j) o.s[j] = f2bf(tile[kk + j][n]);
        *reinterpret_cast<uint4*>(&dst[(size_t)(n0 + n) * K + k0 + kk]) = o.v;
    }
}

// ---------------------------------------------------------------------------
// bf16 MFMA GEMM (m97 structure): C[M,N] = A[M,K] @ Bt[N,K]^T (+epilogue)
// A, Bt row-major K-contiguous. global_load_lds w16 into linear LDS.
// Tile TM x 128, K-step BK. One gload_lds = 512 contiguous elems = 512/BK rows.
// M-block index XCD-swizzled (gridDim.x divisible by 8 in all uses).
// EPI 0: outF = acc + bias           (embedding)
// EPI 1: outB = bf16(acc)            (qkv, no bias)
// EPI 2: outF = res + acc + bias     (attn proj / mlp2, residual, in-place ok)
// EPI 3: outB = bf16(gelu(acc+bias)) (mlp1)
// ---------------------------------------------------------------------------
template <int EPI, int TM, int BK>
__global__ __launch_bounds__(256, 3)
void gemm_bt(const short* __restrict__ A, const short* __restrict__ Bt,
             const float* __restrict__ bias, const float* __restrict__ res,
             float* __restrict__ outF, short* __restrict__ outB,
             int M, int N, int K) {
    constexpr int MB   = TM / 32;             // M fragments per wave
    constexpr int RPC  = 512 / BK;            // rows per 1KB staging chunk
    constexpr int LPR  = BK / 8;              // lanes per row (16B each)
    constexpr int ACH  = (TM / 4) / RPC;      // A chunks per wave
    constexpr int BCH  = 32 / RPC;            // B chunks per wave
    constexpr int KK   = BK / 32;             // MFMA k-fragments per K-step
    __shared__ __align__(16) short As[TM * BK];
    __shared__ __align__(16) short Bs[128 * BK];
    const int tid = threadIdx.x;
    const int lane = tid & 63, w = tid >> 6;
    const int lg = lane >> 4, l15 = lane & 15;
    // XCD swizzle on M dimension (gridDim.x divisible by 8)
    const int gm8 = gridDim.x >> 3;
    const int bm = (blockIdx.x & 7) * gm8 + (blockIdx.x >> 3);
    const int m0 = bm * TM, n0 = blockIdx.y * 128;
    const int wm = (w >> 1) * (TM / 2), wn = (w & 1) * 64;
    const int srow = lane / LPR;              // sub-row within a chunk
    const int scol = (lane % LPR) * 8;        // k-offset (8 bf16 = 16 B)

    const short* aRow = A + (size_t)(m0 + w * (TM / 4) + srow) * K + scol;
    const short* bRow = Bt + (size_t)(n0 + w * 32 + srow) * K + scol;

    f32x4 acc[MB][4];
#pragma unroll
    for (int i = 0; i < MB; ++i)
#pragma unroll
        for (int j = 0; j < 4; ++j) acc[i][j] = f32x4{0.f, 0.f, 0.f, 0.f};

    for (int k0 = 0; k0 < K; k0 += BK) {
#pragma unroll
        for (int c = 0; c < ACH; ++c)
            GLOAD_LDS16(aRow + (size_t)(c * RPC) * K + k0, &As[(w * ACH + c) * 512]);
#pragma unroll
        for (int c = 0; c < BCH; ++c)
            GLOAD_LDS16(bRow + (size_t)(c * RPC) * K + k0, &Bs[(w * BCH + c) * 512]);
        __syncthreads();   // compiler drains vmcnt before s_barrier
#pragma unroll
        for (int kk = 0; kk < KK; ++kk) {
            bf16x8 af[MB], bfr[4];
#pragma unroll
            for (int mb = 0; mb < MB; ++mb)
                af[mb] = *reinterpret_cast<const bf16x8*>(&As[(wm + mb * 16 + l15) * BK + kk * 32 + lg * 8]);
#pragma unroll
            for (int nb = 0; nb < 4; ++nb)
                bfr[nb] = *reinterpret_cast<const bf16x8*>(&Bs[(wn + nb * 16 + l15) * BK + kk * 32 + lg * 8]);
#pragma unroll
            for (int mb = 0; mb < MB; ++mb)
#pragma unroll
                for (int nb = 0; nb < 4; ++nb)
                    acc[mb][nb] = mfma16(af[mb], bfr[nb], acc[mb][nb]);
        }
        __syncthreads();
    }

#pragma unroll
    for (int mb = 0; mb < MB; ++mb)
#pragma unroll
        for (int nb = 0; nb < 4; ++nb)
#pragma unroll
            for (int r = 0; r < 4; ++r) {
                int row = m0 + wm + mb * 16 + lg * 4 + r;
                int col = n0 + wn + nb * 16 + l15;
                size_t idx = (size_t)row * N + col;
                float v = acc[mb][nb][r];
                if constexpr (EPI == 0) {
                    outF[idx] = v + bias[col];
                } else if constexpr (EPI == 1) {
                    outB[idx] = f2bf(v);
                } else if constexpr (EPI == 2) {
                    outF[idx] = res[idx] + v + bias[col];
                } else {
                    outB[idx] = f2bf(gelu_tanh(v + bias[col]));
                }
            }
}

// ---------------------------------------------------------------------------
// LayerNorm over DIM=768, fp32 in -> bf16 out. 1 row per wave, 4 rows/block.
// ---------------------------------------------------------------------------
__global__ __launch_bounds__(256, 4)
void ln_rows(const float* __restrict__ x, const float* __restrict__ w,
             const float* __restrict__ b, short* __restrict__ out) {
    const int wv = threadIdx.x >> 6, lane = threadIdx.x & 63;
    const int row = blockIdx.x * 4 + wv;
    const float* xr = x + (size_t)row * DIM;
    f32x4 v[3];
#pragma unroll
    for (int p = 0; p < 3; ++p)
        v[p] = *reinterpret_cast<const f32x4*>(&xr[p * 256 + lane * 4]);
    float s = 0.f;
#pragma unroll
    for (int p = 0; p < 3; ++p)
#pragma unroll
        for (int j = 0; j < 4; ++j) s += v[p][j];
#pragma unroll
    for (int st = 0; st < 6; ++st) s += __shfl_xor(s, 1 << st, 64);
    const float mean = s * (1.0f / 768.0f);
    float q = 0.f;
#pragma unroll
    for (int p = 0; p < 3; ++p)
#pragma unroll
        for (int j = 0; j < 4; ++j) { float d = v[p][j] - mean; q += d * d; }
#pragma unroll
    for (int st = 0; st < 6; ++st) q += __shfl_xor(q, 1 << st, 64);
    const float inv = 1.0f / sqrtf(q * (1.0f / 768.0f) + 1e-5f);
#pragma unroll
    for (int p = 0; p < 3; ++p) {
        s16x4 ov;
#pragma unroll
        for (int j = 0; j < 4; ++j) {
            int col = p * 256 + lane * 4 + j;
            ov[j] = f2bf((v[p][j] - mean) * inv * w[col] + b[col]);
        }
        *reinterpret_cast<s16x4*>(&out[(size_t)row * DIM + p * 256 + lane * 4]) = ov;
    }
}

// ---------------------------------------------------------------------------
// Fused flash attention. Grid (B*H, SEQ/64), 256 threads (4 waves x 16 q-rows).
// Grid ordered so all q-tiles of one (b,h) land on the same XCD (192 % 8 == 0).
// K/V tile kt+1 global loads issued right after tile kt's staging barrier and
// held in regs (T14 issue-early/write-late): HBM latency hides under compute.
// scores = (Q K^T) * DH^-0.5 + R[b,i];  R[b,i] = |times[b,0]-times[b,i]|
// ---------------------------------------------------------------------------
__global__ __launch_bounds__(256, 3)   // 3 blocks/CU (LDS 27.6KB*3 = 83KB OK)
void attn_fused(const short* __restrict__ qkv, const float* __restrict__ times,
                short* __restrict__ o) {
    __shared__ __align__(16) short Ks[64][72];      // K tile [key][dh]
    __shared__ __align__(16) short Vt[64][72];      // V^T tile [dh][key]
    __shared__ __align__(16) short Ps[4][16][72];   // per-wave P [qrow][key]
    const int tid = threadIdx.x, lane = tid & 63, w = tid >> 6;
    const int lg = lane >> 4, l15 = lane & 15;
    const int q0 = blockIdx.y * 64;
    const int bh = blockIdx.x, b = bh / NH, h = bh % NH;
    const size_t base = (size_t)b * SEQ;

    // per-thread staging coords (constant across tiles)
    const int key0 = tid >> 3,        dc0 = (tid & 7) * 8;          // it=0 (K)
    const int key1 = (tid + 256) >> 3, dc1 = dc0;                   // it=1 (K)
    const int vkey = tid & 63,        vdc0 = (tid >> 6) * 8;        // it=0 (V)
    const int vdc1 = vdc0 + 32;                                     // it=1 (V)

    bf16x8 qf[2];
    {
        int qrow = q0 + w * 16 + l15;
        const short* qp = qkv + (base + qrow) * (size_t)QKVN + h * DHEAD + lg * 8;
        qf[0] = *reinterpret_cast<const bf16x8*>(qp);
        qf[1] = *reinterpret_cast<const bf16x8*>(qp + 32);
    }
    float R4[4];
    {
        float t0 = times[b * SEQ];
#pragma unroll
        for (int r = 0; r < 4; ++r)
            R4[r] = fabsf(t0 - times[b * SEQ + q0 + w * 16 + lg * 4 + r]);
    }
    float m_i[4], l_i[4];
    f32x4 oacc[4];
#pragma unroll
    for (int r = 0; r < 4; ++r) { m_i[r] = -1e30f; l_i[r] = 0.f; }
#pragma unroll
    for (int nb = 0; nb < 4; ++nb) oacc[nb] = f32x4{0.f, 0.f, 0.f, 0.f};

    // prefetch tile 0 into regs
    uint4 kd0, kd1, vd0, vd1;
    {
        const size_t ktok = base;
        kd0 = *reinterpret_cast<const uint4*>(&qkv[(ktok + key0) * (size_t)QKVN + DIM + h * DHEAD + dc0]);
        kd1 = *reinterpret_cast<const uint4*>(&qkv[(ktok + key1) * (size_t)QKVN + DIM + h * DHEAD + dc1]);
        vd0 = *reinterpret_cast<const uint4*>(&qkv[(ktok + vkey) * (size_t)QKVN + 2 * DIM + h * DHEAD + vdc0]);
        vd1 = *reinterpret_cast<const uint4*>(&qkv[(ktok + vkey) * (size_t)QKVN + 2 * DIM + h * DHEAD + vdc1]);
    }

    for (int kt = 0; kt < 8; ++kt) {
        // write staged regs -> LDS
        *reinterpret_cast<uint4*>(&Ks[key0][dc0]) = kd0;
        *reinterpret_cast<uint4*>(&Ks[key1][dc1]) = kd1;
        {
            union { uint4 v; short s[8]; } d;
            d.v = vd0;
#pragma unroll
            for (int j = 0; j < 8; ++j) Vt[vdc0 + j][vkey] = d.s[j];
            d.v = vd1;
#pragma unroll
            for (int j = 0; j < 8; ++j) Vt[vdc1 + j][vkey] = d.s[j];
        }
        __syncthreads();
        // issue next tile's global loads (overlap with compute below)
        if (kt < 7) {
            const size_t ktok = base + (kt + 1) * 64;
            kd0 = *reinterpret_cast<const uint4*>(&qkv[(ktok + key0) * (size_t)QKVN + DIM + h * DHEAD + dc0]);
            kd1 = *reinterpret_cast<const uint4*>(&qkv[(ktok + key1) * (size_t)QKVN + DIM + h * DHEAD + dc1]);
            vd0 = *reinterpret_cast<const uint4*>(&qkv[(ktok + vkey) * (size_t)QKVN + 2 * DIM + h * DHEAD + vdc0]);
            vd1 = *reinterpret_cast<const uint4*>(&qkv[(ktok + vkey) * (size_t)QKVN + 2 * DIM + h * DHEAD + vdc1]);
        }

        float sv[4][4];
#pragma unroll
        for (int c = 0; c < 4; ++c) {
            f32x4 s = f32x4{0.f, 0.f, 0.f, 0.f};
#pragma unroll
            for (int kb = 0; kb < 2; ++kb) {
                bf16x8 kf = *reinterpret_cast<const bf16x8*>(&Ks[c * 16 + l15][kb * 32 + lg * 8]);
                s = mfma16(qf[kb], kf, s);
            }
#pragma unroll
            for (int r = 0; r < 4; ++r) sv[c][r] = s[r] * 0.125f + R4[r];
        }
        float mx[4], m_new[4], sc[4], rs[4], p[4][4];
#pragma unroll
        for (int r = 0; r < 4; ++r)
            mx[r] = fmaxf(fmaxf(sv[0][r], sv[1][r]), fmaxf(sv[2][r], sv[3][r]));
#pragma unroll
        for (int st = 0; st < 4; ++st)
#pragma unroll
            for (int r = 0; r < 4; ++r) mx[r] = fmaxf(mx[r], __shfl_xor(mx[r], 1 << st, 64));
#pragma unroll
        for (int r = 0; r < 4; ++r) {
            m_new[r] = fmaxf(m_i[r], mx[r]);
            sc[r] = __expf(m_i[r] - m_new[r]);
            l_i[r] *= sc[r];
        }
#pragma unroll
        for (int c = 0; c < 4; ++c)
#pragma unroll
            for (int r = 0; r < 4; ++r) p[c][r] = __expf(sv[c][r] - m_new[r]);
#pragma unroll
        for (int r = 0; r < 4; ++r) rs[r] = p[0][r] + p[1][r] + p[2][r] + p[3][r];
#pragma unroll
        for (int st = 0; st < 4; ++st)
#pragma unroll
            for (int r = 0; r < 4; ++r) rs[r] += __shfl_xor(rs[r], 1 << st, 64);
#pragma unroll
        for (int r = 0; r < 4; ++r) { l_i[r] += rs[r]; m_i[r] = m_new[r]; }
#pragma unroll
        for (int nb = 0; nb < 4; ++nb)
#pragma unroll
            for (int r = 0; r < 4; ++r) oacc[nb][r] *= sc[r];
#pragma unroll
        for (int c = 0; c < 4; ++c)
#pragma unroll
            for (int r = 0; r < 4; ++r)
                Ps[w][lg * 4 + r][c * 16 + l15] = f2bf(p[c][r]);
        __syncthreads();
#pragma unroll
        for (int kb = 0; kb < 2; ++kb) {
            bf16x8 pf = *reinterpret_cast<const bf16x8*>(&Ps[w][l15][kb * 32 + lg * 8]);
#pragma unroll
            for (int nb = 0; nb < 4; ++nb) {
                bf16x8 vf = *reinterpret_cast<const bf16x8*>(&Vt[nb * 16 + l15][kb * 32 + lg * 8]);
                oacc[nb] = mfma16(pf, vf, oacc[nb]);
            }
        }
        __syncthreads();
    }
#pragma unroll
    for (int r = 0; r < 4; ++r) {
        float inv = 1.0f / l_i[r];
        int row = q0 + w * 16 + lg * 4 + r;
        size_t ob = (base + row) * (size_t)DIM + h * DHEAD;
#pragma unroll
        for (int nb = 0; nb < 4; ++nb)
            o[ob + nb * 16 + l15] = f2bf(oacc[nb][r] * inv);
    }
}

// ---------------------------------------------------------------------------
// Deterministic mean-pool: pooled[b][c] = sum_t x[b][t][c]. Grid (BATCH, 3).
// ---------------------------------------------------------------------------
__global__ __launch_bounds__(256)
void pool_kernel(const float* __restrict__ x, float* __restrict__ pooled) {
    const int b = blockIdx.x;
    const int c = blockIdx.y * 256 + threadIdx.x;
    const float* xp = x + (size_t)b * SEQ * DIM + c;
    float a = 0.f;
#pragma unroll 8
    for (int t = 0; t < SEQ; ++t) a += xp[(size_t)t * DIM];
    pooled[b * DIM + c] = a;
}

// ---------------------------------------------------------------------------
// Head stage 1: xln[b] = LN(pooled[b]/512)*hln_w + hln_b. 16 blocks x 256.
// ---------------------------------------------------------------------------
__global__ __launch_bounds__(256)
void head_ln(const float* __restrict__ pooled,
             const float* __restrict__ hw, const float* __restrict__ hb,
             float* __restrict__ xln) {
    __shared__ float xb[768];
    __shared__ float red[256];
    const int b = blockIdx.x, tid = threadIdx.x;
#pragma unroll
    for (int p = 0; p < 3; ++p)
        xb[tid + 256 * p] = pooled[b * DIM + tid + 256 * p] * (1.0f / 512.0f);
    __syncthreads();
    float part = xb[tid] + xb[tid + 256] + xb[tid + 512];
    red[tid] = part; __syncthreads();
    for (int s = 128; s > 0; s >>= 1) { if (tid < s) red[tid] += red[tid + s]; __syncthreads(); }
    float mean = red[0] * (1.0f / 768.0f);
    __syncthreads();
    float vp = 0.f;
#pragma unroll
    for (int p = 0; p < 3; ++p) { float d = xb[tid + 256 * p] - mean; vp += d * d; }
    red[tid] = vp; __syncthreads();
    for (int s = 128; s > 0; s >>= 1) { if (tid < s) red[tid] += red[tid + s]; __syncthreads(); }
    float inv = 1.0f / sqrtf(red[0] * (1.0f / 768.0f) + 1e-5f);
    __syncthreads();
#pragma unroll
    for (int p = 0; p < 3; ++p) {
        int i = tid + 256 * p;
        xln[b * DIM + i] = (xb[i] - mean) * inv * hw[i] + hb[i];
    }
}

// ---------------------------------------------------------------------------
// Head stage 2: h1 = xln @ hw1 + hb1. Grid (BATCH, 12), 256 thr.
// ---------------------------------------------------------------------------
__global__ __launch_bounds__(256)
void head_mm1(const float* __restrict__ xln, const float* __restrict__ w1,
              const float* __restrict__ b1, float* __restrict__ h1) {
    __shared__ float xs[768];
    __shared__ float red[4][64];
    const int b = blockIdx.x, nc = blockIdx.y, tid = threadIdx.x;
    const int nl = tid & 63, q = tid >> 6;       // col-local, k-quarter
#pragma unroll
    for (int p = 0; p < 3; ++p) xs[tid + 256 * p] = xln[b * DIM + tid + 256 * p];
    __syncthreads();
    const int n = nc * 64 + nl;
    float a = 0.f;
    const float* wp = w1 + (size_t)(q * 192) * DIM + n;
#pragma unroll 8
    for (int k = 0; k < 192; ++k) a += xs[q * 192 + k] * wp[(size_t)k * DIM];
    red[q][nl] = a;
    __syncthreads();
    if (q == 0) h1[b * DIM + n] = red[0][nl] + red[1][nl] + red[2][nl] + red[3][nl] + b1[n];
}

// ---------------------------------------------------------------------------
// Head stage 3: out = h1 @ hw2 + hb2. 16 blocks x 256 thr, 2 outputs each.
// ---------------------------------------------------------------------------
__global__ __launch_bounds__(256)
void head_mm2(const float* __restrict__ h1, const float* __restrict__ w2,
              const float* __restrict__ b2, float* __restrict__ out) {
    __shared__ float red[256];
    const int b = blockIdx.x, tid = threadIdx.x;
    float p0 = 0.f, p1 = 0.f;
    for (int k = tid; k < 768; k += 256) {
        float hv = h1[b * DIM + k];
        p0 += hv * w2[k * 2]; p1 += hv * w2[k * 2 + 1];
    }
    red[tid] = p0; __syncthreads();
    for (int s = 128; s > 0; s >>= 1) { if (tid < s) red[tid] += red[tid + s]; __syncthreads(); }
    if (tid == 0) out[b * 2 + 0] = red[0] + b2[0];
    __syncthreads();
    red[tid] = p1; __syncthreads();
    for (int s = 128; s > 0; s >>= 1) { if (tid < s) red[tid] += red[tid + s]; __syncthreads(); }
    if (tid == 0) out[b * 2 + 1] = red[0] + b2[1];
}

// ---------------------------------------------------------------------------
extern "C" void kernel_launch(void* const* d_in, const int* in_sizes, int n_in,
                              void* d_out, int out_size, void* d_ws, size_t ws_size,
                              hipStream_t stream) {
    (void)in_sizes; (void)n_in; (void)out_size; (void)ws_size;
    const float* feat  = (const float*)d_in[0];
    const float* times = (const float*)d_in[1];
    const float* emb_w = (const float*)d_in[2];
    const float* emb_b = (const float*)d_in[3];
    const float* ln1_w = (const float*)d_in[4];
    const float* ln1_b = (const float*)d_in[5];
    const float* w_qkv = (const float*)d_in[6];
    const float* w_o   = (const float*)d_in[7];
    const float* b_o   = (const float*)d_in[8];
    const float* ln2_w = (const float*)d_in[9];
    const float* ln2_b = (const float*)d_in[10];
    const float* w1    = (const float*)d_in[11];
    const float* b1    = (const float*)d_in[12];
    const float* w2    = (const float*)d_in[13];
    const float* b2    = (const float*)d_in[14];
    const float* hln_w = (const float*)d_in[15];
    const float* hln_b = (const float*)d_in[16];
    const float* hw1   = (const float*)d_in[17];
    const float* hb1   = (const float*)d_in[18];
    const float* hw2   = (const float*)d_in[19];
    const float* hb2   = (const float*)d_in[20];
    float* out = (float*)d_out;

    char* ws = (char*)d_ws;
    size_t off = 0;
    auto alloc = [&](size_t bytes) {
        char* p = ws + off; off += (bytes + 255) & ~(size_t)255; return p;
    };
    short* embWT = (short*)alloc((size_t)FDIM * DIM * 2);          // [DIM][FDIM]
    short* wqkvT = (short*)alloc((size_t)NLAYER * DIM * QKVN * 2); // [L][QKVN][DIM]
    short* woT   = (short*)alloc((size_t)NLAYER * DIM * DIM * 2);  // [L][DIM][DIM]
    short* w1T   = (short*)alloc((size_t)NLAYER * DIM * DMLP * 2); // [L][DMLP][DIM]
    short* w2T   = (short*)alloc((size_t)NLAYER * DMLP * DIM * 2); // [L][DIM][DMLP]
    float* x     = (float*)alloc((size_t)TOK * DIM * 4);
    short* xn    = (short*)alloc((size_t)TOK * DIM * 2);
    short* qkvB  = (short*)alloc((size_t)TOK * QKVN * 2);
    short* oB    = (short*)alloc((size_t)TOK * DIM * 2);
    short* hB    = (short*)alloc((size_t)TOK * DMLP * 2);          // 50 MB
    float* pooled= (float*)alloc((size_t)BATCH * DIM * 4);
    float* xlnH  = (float*)alloc((size_t)BATCH * DIM * 4);
    float* h1H   = (float*)alloc((size_t)BATCH * DIM * 4);
    // featB aliases hB: featB is dead after the embedding GEMM; hB's first
    // write (layer-0 mlp1) is strictly later. Saves 16 MB of workspace.
    short* featB = hB;   // TOK*FDIM*2 = 32 MB <= hB's 50 MB

    // feat: plain convert (already K-contiguous as GEMM A operand)
    {
        int n4 = (int)((size_t)TOK * FDIM / 4);
        cvt_f32_bf16<<<2048, 256, 0, stream>>>(feat, featB, n4);
    }
    // weights: transpose + convert -> [N][K] bf16
    transpose_cvt<<<dim3(FDIM / 64, DIM / 64, 1), 256, 0, stream>>>(emb_w, embWT, FDIM, DIM);
    transpose_cvt<<<dim3(DIM / 64, QKVN / 64, NLAYER), 256, 0, stream>>>(w_qkv, wqkvT, DIM, QKVN);
    transpose_cvt<<<dim3(DIM / 64, DIM / 64, NLAYER), 256, 0, stream>>>(w_o, woT, DIM, DIM);
    transpose_cvt<<<dim3(DIM / 64, DMLP / 64, NLAYER), 256, 0, stream>>>(w1, w1T, DIM, DMLP);
    transpose_cvt<<<dim3(DMLP / 64, DIM / 64, NLAYER), 256, 0, stream>>>(w2, w2T, DMLP, DIM);

    // embedding: x = feat @ emb_w + emb_b  (TM=64/BK=128: 768 blocks, 8 K-steps)
    gemm_bt<0, 64, 128><<<dim3(TOK / 64, DIM / 128), 256, 0, stream>>>(
        featB, embWT, emb_b, nullptr, x, nullptr, TOK, DIM, FDIM);

    for (int l = 0; l < NLAYER; ++l) {
        ln_rows<<<TOK / 4, 256, 0, stream>>>(x, ln1_w + l * DIM, ln1_b + l * DIM, xn);
        gemm_bt<1, 128, 64><<<dim3(TOK / 128, QKVN / 128), 256, 0, stream>>>(
            xn, wqkvT + (size_t)l * DIM * QKVN, nullptr, nullptr, nullptr, qkvB, TOK, QKVN, DIM);
        attn_fused<<<dim3(BATCH * NH, SEQ / 64), 256, 0, stream>>>(qkvB, times, oB);
        gemm_bt<2, 64, 128><<<dim3(TOK / 64, DIM / 128), 256, 0, stream>>>(
            oB, woT + (size_t)l * DIM * DIM, b_o + l * DIM, x, x, nullptr, TOK, DIM, DIM);
        ln_rows<<<TOK / 4, 256, 0, stream>>>(x, ln2_w + l * DIM, ln2_b + l * DIM, xn);
        gemm_bt<3, 128, 64><<<dim3(TOK / 128, DMLP / 128), 256, 0, stream>>>(
            xn, w1T + (size_t)l * DIM * DMLP, b1 + l * DMLP, nullptr, nullptr, hB, TOK, DMLP, DIM);
        gemm_bt<2, 64, 128><<<dim3(TOK / 64, DIM / 128), 256, 0, stream>>>(
            hB, w2T + (size_t)l * DMLP * DIM, b2 + l * DIM, x, x, nullptr, TOK, DIM, DMLP);
    }

    pool_kernel<<<dim3(BATCH, 3), 256, 0, stream>>>(x, pooled);
    head_ln<<<BATCH, 256, 0, stream>>>(pooled, hln_w, hln_b, xlnH);
    head_mm1<<<dim3(BATCH, 12), 256, 0, stream>>>(xlnH, hw1, hb1, h1H);
    head_mm2<<<BATCH, 256, 0, stream>>>(h1H, hw2, hb2, out);
}

// Round 11
// 3344.273 us; speedup vs baseline: 1.2875x; 1.2875x over previous
//
#include <hip/hip_runtime.h>
#include <hip/hip_bf16.h>
#include <cstdint>
#include <cstddef>

// ---------------------------------------------------------------------------
// TimeAwareFeatViT forward, MI355X (gfx950).
// R10 = R9 resubmitted (R9 bench was an infra failure, kernel never ran).
// R9: revert R8's BK=128 regression (conflicts 2.1e7->5e7, MfmaUtil 12%) back
// to R7 (TM=64/BK=64 for N=768 GEMMs, TM=128/BK=64 qkv/mlp1), and add the T2
// XOR swizzle with global_load_lds (rule #21c): linear LDS dest + per-lane
// pre-swizzled GLOBAL source (slot ^= srow) + swizzled ds_read (slot ^= row&7).
// R8 counters showed 16-way bank conflicts = ~43% of GEMM wall time.
// ---------------------------------------------------------------------------

typedef __attribute__((ext_vector_type(8))) short bf16x8;  // 8 bf16 = 4 VGPRs
typedef __attribute__((ext_vector_type(4))) short s16x4;
typedef __attribute__((ext_vector_type(4))) float f32x4;

#define DEVFN __device__ __forceinline__

constexpr int BATCH = 16, SEQ = 512, FDIM = 1024, DIM = 768, NLAYER = 12;
constexpr int NH = 12, DHEAD = 64, DMLP = 3072;
constexpr int TOK = BATCH * SEQ;      // 8192
constexpr int QKVN = 3 * DIM;         // 2304

DEVFN short f2bf(float f) {           // fp32 -> bf16 bits, RNE
    union { float f; uint32_t u; } v; v.f = f;
    uint32_t r = v.u + 0x7FFFu + ((v.u >> 16) & 1u);
    return (short)(r >> 16);
}

DEVFN f32x4 mfma16(bf16x8 a, bf16x8 b, f32x4 c) {
    return __builtin_amdgcn_mfma_f32_16x16x32_bf16(a, b, c, 0, 0, 0);
}

// jax.nn.gelu approximate=True: 0.5x(1+tanh(c(x+0.044715x^3))) == x*sigmoid(2c(x+0.044715x^3))
DEVFN float gelu_tanh(float x) {
    const float c2 = 1.5957691216057308f;   // 2*sqrt(2/pi)
    float u = c2 * (x + 0.044715f * x * x * x);
    return x / (1.0f + __expf(-u));
}

// async global->LDS, 16B per lane; lds base must be wave-uniform
#define GLOAD_LDS16(gp, lp)                                                     \
    __builtin_amdgcn_global_load_lds(                                           \
        (const __attribute__((address_space(1))) void*)(gp),                    \
        (__attribute__((address_space(3))) void*)(lp), 16, 0, 0)

// ---------------------------------------------------------------------------
// fp32 -> bf16 elementwise convert (vectorized, grid-stride) — for feat
// ---------------------------------------------------------------------------
__global__ void cvt_f32_bf16(const float* __restrict__ in, short* __restrict__ out, int n4) {
    int i = blockIdx.x * blockDim.x + threadIdx.x;
    int stride = gridDim.x * blockDim.x;
    for (; i < n4; i += stride) {
        f32x4 v = reinterpret_cast<const f32x4*>(in)[i];
        s16x4 o;
        o[0] = f2bf(v[0]); o[1] = f2bf(v[1]); o[2] = f2bf(v[2]); o[3] = f2bf(v[3]);
        reinterpret_cast<s16x4*>(out)[i] = o;
    }
}

// ---------------------------------------------------------------------------
// Transpose + convert: in [L][K][N] f32 -> out [L][N][K] bf16. 64x64 LDS tile,
// both sides coalesced. Grid (K/64, N/64, L), 256 threads.
// ---------------------------------------------------------------------------
__global__ __launch_bounds__(256)
void transpose_cvt(const float* __restrict__ in, short* __restrict__ out, int K, int N) {
    __shared__ float tile[64][65];
    const size_t lo = (size_t)blockIdx.z * K * N;
    const float* src = in + lo;
    short* dst = out + lo;
    const int k0 = blockIdx.x * 64, n0 = blockIdx.y * 64;
    const int tid = threadIdx.x;
#pragma unroll
    for (int p = 0; p < 4; ++p) {                      // read 16 k-rows / pass
        int r = p * 16 + (tid >> 4);
        int c = (tid & 15) * 4;
        f32x4 v = *reinterpret_cast<const f32x4*>(&src[(size_t)(k0 + r) * N + n0 + c]);
        tile[r][c] = v[0]; tile[r][c + 1] = v[1]; tile[r][c + 2] = v[2]; tile[r][c + 3] = v[3];
    }
    __syncthreads();
#pragma unroll
    for (int p = 0; p < 2; ++p) {                      // write 32 n-rows / pass
        int n = p * 32 + (tid >> 3);
        int kk = (tid & 7) * 8;
        union { uint4 v; short s[8]; } o;
#pragma unroll
        for (int j = 0; j < 8; ++j) o.s[j] = f2bf(tile[kk + j][n]);
        *reinterpret_cast<uint4*>(&dst[(size_t)(n0 + n) * K + k0 + kk]) = o.v;
    }
}

// ---------------------------------------------------------------------------
// bf16 MFMA GEMM (m97 structure + T2 swizzle): C = A[M,K] @ Bt[N,K]^T (+epi)
// A, Bt row-major K-contiguous. Staging: global_load_lds w16, linear LDS dest,
// per-lane global source pre-swizzled (16B slot ^= srow within each 8-row
// chunk). ds_read applies the same XOR (slot ^= row&7): the 16 fragment lanes
// then hit 8 distinct bank-quads 2-way (free) instead of one bank 16-way.
// Tile TM x 128, BK=64. TM=64: 4 waves of 32x64 (N=768 GEMMs, 768 blocks =
// 3/CU). TM=128: 4 waves of 64x64 (qkv/mlp1).
// EPI 0: outF = acc + bias           (embedding)
// EPI 1: outB = bf16(acc)            (qkv, no bias)
// EPI 2: outF = res + acc + bias     (attn proj / mlp2, residual, in-place ok)
// EPI 3: outB = bf16(gelu(acc+bias)) (mlp1)
// ---------------------------------------------------------------------------
template <int EPI, int TM>
__global__ __launch_bounds__(256, 3)
void gemm_bt(const short* __restrict__ A, const short* __restrict__ Bt,
             const float* __restrict__ bias, const float* __restrict__ res,
             float* __restrict__ outF, short* __restrict__ outB,
             int M, int N, int K) {
    constexpr int MB  = TM / 32;   // M fragments per wave
    constexpr int ACH = TM / 32;   // A staging chunks per wave (8 rows each)
    __shared__ __align__(16) short As[TM * 64];
    __shared__ __align__(16) short Bs[128 * 64];
    const int tid = threadIdx.x;
    const int lane = tid & 63, w = tid >> 6;
    const int lg = lane >> 4, l15 = lane & 15;
    // XCD swizzle on M dimension (gridDim.x divisible by 8)
    const int gm8 = gridDim.x >> 3;
    const int bm = (blockIdx.x & 7) * gm8 + (blockIdx.x >> 3);
    const int m0 = bm * TM, n0 = blockIdx.y * 128;
    const int wm = (w >> 1) * (TM / 2), wn = (w & 1) * 64;
    const int srow = lane >> 3;                    // row within 8-row chunk
    const int scol = ((lane & 7) ^ srow) * 8;      // XOR-swizzled 16B slot

    const short* aRow = A + (size_t)(m0 + w * (TM / 4) + srow) * K + scol;
    const short* bRow = Bt + (size_t)(n0 + w * 32 + srow) * K + scol;

    const int rsw = l15 & 7;                       // read-side XOR operand

    f32x4 acc[MB][4];
#pragma unroll
    for (int i = 0; i < MB; ++i)
#pragma unroll
        for (int j = 0; j < 4; ++j) acc[i][j] = f32x4{0.f, 0.f, 0.f, 0.f};

    for (int k0 = 0; k0 < K; k0 += 64) {
#pragma unroll
        for (int c = 0; c < ACH; ++c)
            GLOAD_LDS16(aRow + (size_t)(c * 8) * K + k0, &As[(w * ACH + c) * 512]);
#pragma unroll
        for (int c = 0; c < 4; ++c)
            GLOAD_LDS16(bRow + (size_t)(c * 8) * K + k0, &Bs[(w * 4 + c) * 512]);
        __syncthreads();   // compiler drains vmcnt before s_barrier
#pragma unroll
        for (int kk = 0; kk < 2; ++kk) {
            const int sl = ((kk * 4 + lg) ^ rsw) * 8;   // swizzled k-slot
            bf16x8 af[MB], bfr[4];
#pragma unroll
            for (int mb = 0; mb < MB; ++mb)
                af[mb] = *reinterpret_cast<const bf16x8*>(&As[(wm + mb * 16 + l15) * 64 + sl]);
#pragma unroll
            for (int nb = 0; nb < 4; ++nb)
                bfr[nb] = *reinterpret_cast<const bf16x8*>(&Bs[(wn + nb * 16 + l15) * 64 + sl]);
#pragma unroll
            for (int mb = 0; mb < MB; ++mb)
#pragma unroll
                for (int nb = 0; nb < 4; ++nb)
                    acc[mb][nb] = mfma16(af[mb], bfr[nb], acc[mb][nb]);
        }
        __syncthreads();
    }

#pragma unroll
    for (int mb = 0; mb < MB; ++mb)
#pragma unroll
        for (int nb = 0; nb < 4; ++nb)
#pragma unroll
            for (int r = 0; r < 4; ++r) {
                int row = m0 + wm + mb * 16 + lg * 4 + r;
                int col = n0 + wn + nb * 16 + l15;
                size_t idx = (size_t)row * N + col;
                float v = acc[mb][nb][r];
                if constexpr (EPI == 0) {
                    outF[idx] = v + bias[col];
                } else if constexpr (EPI == 1) {
                    outB[idx] = f2bf(v);
                } else if constexpr (EPI == 2) {
                    outF[idx] = res[idx] + v + bias[col];
                } else {
                    outB[idx] = f2bf(gelu_tanh(v + bias[col]));
                }
            }
}

// ---------------------------------------------------------------------------
// LayerNorm over DIM=768, fp32 in -> bf16 out. 1 row per wave, 4 rows/block.
// ---------------------------------------------------------------------------
__global__ __launch_bounds__(256, 4)
void ln_rows(const float* __restrict__ x, const float* __restrict__ w,
             const float* __restrict__ b, short* __restrict__ out) {
    const int wv = threadIdx.x >> 6, lane = threadIdx.x & 63;
    const int row = blockIdx.x * 4 + wv;
    const float* xr = x + (size_t)row * DIM;
    f32x4 v[3];
#pragma unroll
    for (int p = 0; p < 3; ++p)
        v[p] = *reinterpret_cast<const f32x4*>(&xr[p * 256 + lane * 4]);
    float s = 0.f;
#pragma unroll
    for (int p = 0; p < 3; ++p)
#pragma unroll
        for (int j = 0; j < 4; ++j) s += v[p][j];
#pragma unroll
    for (int st = 0; st < 6; ++st) s += __shfl_xor(s, 1 << st, 64);
    const float mean = s * (1.0f / 768.0f);
    float q = 0.f;
#pragma unroll
    for (int p = 0; p < 3; ++p)
#pragma unroll
        for (int j = 0; j < 4; ++j) { float d = v[p][j] - mean; q += d * d; }
#pragma unroll
    for (int st = 0; st < 6; ++st) q += __shfl_xor(q, 1 << st, 64);
    const float inv = 1.0f / sqrtf(q * (1.0f / 768.0f) + 1e-5f);
#pragma unroll
    for (int p = 0; p < 3; ++p) {
        s16x4 ov;
#pragma unroll
        for (int j = 0; j < 4; ++j) {
            int col = p * 256 + lane * 4 + j;
            ov[j] = f2bf((v[p][j] - mean) * inv * w[col] + b[col]);
        }
        *reinterpret_cast<s16x4*>(&out[(size_t)row * DIM + p * 256 + lane * 4]) = ov;
    }
}

// ---------------------------------------------------------------------------
// Fused flash attention. Grid (B*H, SEQ/64), 256 threads (4 waves x 16 q-rows).
// Grid ordered so all q-tiles of one (b,h) land on the same XCD (192 % 8 == 0).
// K/V tile kt+1 global loads issued right after tile kt's staging barrier and
// held in regs (T14 issue-early/write-late): HBM latency hides under compute.
// scores = (Q K^T) * DH^-0.5 + R[b,i];  R[b,i] = |times[b,0]-times[b,i]|
// ---------------------------------------------------------------------------
__global__ __launch_bounds__(256, 3)   // 3 blocks/CU (LDS 27.6KB*3 = 83KB OK)
void attn_fused(const short* __restrict__ qkv, const float* __restrict__ times,
                short* __restrict__ o) {
    __shared__ __align__(16) short Ks[64][72];      // K tile [key][dh]
    __shared__ __align__(16) short Vt[64][72];      // V^T tile [dh][key]
    __shared__ __align__(16) short Ps[4][16][72];   // per-wave P [qrow][key]
    const int tid = threadIdx.x, lane = tid & 63, w = tid >> 6;
    const int lg = lane >> 4, l15 = lane & 15;
    const int q0 = blockIdx.y * 64;
    const int bh = blockIdx.x, b = bh / NH, h = bh % NH;
    const size_t base = (size_t)b * SEQ;

    // per-thread staging coords (constant across tiles)
    const int key0 = tid >> 3,        dc0 = (tid & 7) * 8;          // it=0 (K)
    const int key1 = (tid + 256) >> 3, dc1 = dc0;                   // it=1 (K)
    const int vkey = tid & 63,        vdc0 = (tid >> 6) * 8;        // it=0 (V)
    const int vdc1 = vdc0 + 32;                                     // it=1 (V)

    bf16x8 qf[2];
    {
        int qrow = q0 + w * 16 + l15;
        const short* qp = qkv + (base + qrow) * (size_t)QKVN + h * DHEAD + lg * 8;
        qf[0] = *reinterpret_cast<const bf16x8*>(qp);
        qf[1] = *reinterpret_cast<const bf16x8*>(qp + 32);
    }
    float R4[4];
    {
        float t0 = times[b * SEQ];
#pragma unroll
        for (int r = 0; r < 4; ++r)
            R4[r] = fabsf(t0 - times[b * SEQ + q0 + w * 16 + lg * 4 + r]);
    }
    float m_i[4], l_i[4];
    f32x4 oacc[4];
#pragma unroll
    for (int r = 0; r < 4; ++r) { m_i[r] = -1e30f; l_i[r] = 0.f; }
#pragma unroll
    for (int nb = 0; nb < 4; ++nb) oacc[nb] = f32x4{0.f, 0.f, 0.f, 0.f};

    // prefetch tile 0 into regs
    uint4 kd0, kd1, vd0, vd1;
    {
        const size_t ktok = base;
        kd0 = *reinterpret_cast<const uint4*>(&qkv[(ktok + key0) * (size_t)QKVN + DIM + h * DHEAD + dc0]);
        kd1 = *reinterpret_cast<const uint4*>(&qkv[(ktok + key1) * (size_t)QKVN + DIM + h * DHEAD + dc1]);
        vd0 = *reinterpret_cast<const uint4*>(&qkv[(ktok + vkey) * (size_t)QKVN + 2 * DIM + h * DHEAD + vdc0]);
        vd1 = *reinterpret_cast<const uint4*>(&qkv[(ktok + vkey) * (size_t)QKVN + 2 * DIM + h * DHEAD + vdc1]);
    }

    for (int kt = 0; kt < 8; ++kt) {
        // write staged regs -> LDS
        *reinterpret_cast<uint4*>(&Ks[key0][dc0]) = kd0;
        *reinterpret_cast<uint4*>(&Ks[key1][dc1]) = kd1;
        {
            union { uint4 v; short s[8]; } d;
            d.v = vd0;
#pragma unroll
            for (int j = 0; j < 8; ++j) Vt[vdc0 + j][vkey] = d.s[j];
            d.v = vd1;
#pragma unroll
            for (int j = 0; j < 8; ++j) Vt[vdc1 + j][vkey] = d.s[j];
        }
        __syncthreads();
        // issue next tile's global loads (overlap with compute below)
        if (kt < 7) {
            const size_t ktok = base + (kt + 1) * 64;
            kd0 = *reinterpret_cast<const uint4*>(&qkv[(ktok + key0) * (size_t)QKVN + DIM + h * DHEAD + dc0]);
            kd1 = *reinterpret_cast<const uint4*>(&qkv[(ktok + key1) * (size_t)QKVN + DIM + h * DHEAD + dc1]);
            vd0 = *reinterpret_cast<const uint4*>(&qkv[(ktok + vkey) * (size_t)QKVN + 2 * DIM + h * DHEAD + vdc0]);
            vd1 = *reinterpret_cast<const uint4*>(&qkv[(ktok + vkey) * (size_t)QKVN + 2 * DIM + h * DHEAD + vdc1]);
        }

        float sv[4][4];
#pragma unroll
        for (int c = 0; c < 4; ++c) {
            f32x4 s = f32x4{0.f, 0.f, 0.f, 0.f};
#pragma unroll
            for (int kb = 0; kb < 2; ++kb) {
                bf16x8 kf = *reinterpret_cast<const bf16x8*>(&Ks[c * 16 + l15][kb * 32 + lg * 8]);
                s = mfma16(qf[kb], kf, s);
            }
#pragma unroll
            for (int r = 0; r < 4; ++r) sv[c][r] = s[r] * 0.125f + R4[r];
        }
        float mx[4], m_new[4], sc[4], rs[4], p[4][4];
#pragma unroll
        for (int r = 0; r < 4; ++r)
            mx[r] = fmaxf(fmaxf(sv[0][r], sv[1][r]), fmaxf(sv[2][r], sv[3][r]));
#pragma unroll
        for (int st = 0; st < 4; ++st)
#pragma unroll
            for (int r = 0; r < 4; ++r) mx[r] = fmaxf(mx[r], __shfl_xor(mx[r], 1 << st, 64));
#pragma unroll
        for (int r = 0; r < 4; ++r) {
            m_new[r] = fmaxf(m_i[r], mx[r]);
            sc[r] = __expf(m_i[r] - m_new[r]);
            l_i[r] *= sc[r];
        }
#pragma unroll
        for (int c = 0; c < 4; ++c)
#pragma unroll
            for (int r = 0; r < 4; ++r) p[c][r] = __expf(sv[c][r] - m_new[r]);
#pragma unroll
        for (int r = 0; r < 4; ++r) rs[r] = p[0][r] + p[1][r] + p[2][r] + p[3][r];
#pragma unroll
        for (int st = 0; st < 4; ++st)
#pragma unroll
            for (int r = 0; r < 4; ++r) rs[r] += __shfl_xor(rs[r], 1 << st, 64);
#pragma unroll
        for (int r = 0; r < 4; ++r) { l_i[r] += rs[r]; m_i[r] = m_new[r]; }
#pragma unroll
        for (int nb = 0; nb < 4; ++nb)
#pragma unroll
            for (int r = 0; r < 4; ++r) oacc[nb][r] *= sc[r];
#pragma unroll
        for (int c = 0; c < 4; ++c)
#pragma unroll
            for (int r = 0; r < 4; ++r)
                Ps[w][lg * 4 + r][c * 16 + l15] = f2bf(p[c][r]);
        __syncthreads();
#pragma unroll
        for (int kb = 0; kb < 2; ++kb) {
            bf16x8 pf = *reinterpret_cast<const bf16x8*>(&Ps[w][l15][kb * 32 + lg * 8]);
#pragma unroll
            for (int nb = 0; nb < 4; ++nb) {
                bf16x8 vf = *reinterpret_cast<const bf16x8*>(&Vt[nb * 16 + l15][kb * 32 + lg * 8]);
                oacc[nb] = mfma16(pf, vf, oacc[nb]);
            }
        }
        __syncthreads();
    }
#pragma unroll
    for (int r = 0; r < 4; ++r) {
        float inv = 1.0f / l_i[r];
        int row = q0 + w * 16 + lg * 4 + r;
        size_t ob = (base + row) * (size_t)DIM + h * DHEAD;
#pragma unroll
        for (int nb = 0; nb < 4; ++nb)
            o[ob + nb * 16 + l15] = f2bf(oacc[nb][r] * inv);
    }
}

// ---------------------------------------------------------------------------
// Deterministic mean-pool: pooled[b][c] = sum_t x[b][t][c]. Grid (BATCH, 3).
// ---------------------------------------------------------------------------
__global__ __launch_bounds__(256)
void pool_kernel(const float* __restrict__ x, float* __restrict__ pooled) {
    const int b = blockIdx.x;
    const int c = blockIdx.y * 256 + threadIdx.x;
    const float* xp = x + (size_t)b * SEQ * DIM + c;
    float a = 0.f;
#pragma unroll 8
    for (int t = 0; t < SEQ; ++t) a += xp[(size_t)t * DIM];
    pooled[b * DIM + c] = a;
}

// ---------------------------------------------------------------------------
// Head stage 1: xln[b] = LN(pooled[b]/512)*hln_w + hln_b. 16 blocks x 256.
// ---------------------------------------------------------------------------
__global__ __launch_bounds__(256)
void head_ln(const float* __restrict__ pooled,
             const float* __restrict__ hw, const float* __restrict__ hb,
             float* __restrict__ xln) {
    __shared__ float xb[768];
    __shared__ float red[256];
    const int b = blockIdx.x, tid = threadIdx.x;
#pragma unroll
    for (int p = 0; p < 3; ++p)
        xb[tid + 256 * p] = pooled[b * DIM + tid + 256 * p] * (1.0f / 512.0f);
    __syncthreads();
    float part = xb[tid] + xb[tid + 256] + xb[tid + 512];
    red[tid] = part; __syncthreads();
    for (int s = 128; s > 0; s >>= 1) { if (tid < s) red[tid] += red[tid + s]; __syncthreads(); }
    float mean = red[0] * (1.0f / 768.0f);
    __syncthreads();
    float vp = 0.f;
#pragma unroll
    for (int p = 0; p < 3; ++p) { float d = xb[tid + 256 * p] - mean; vp += d * d; }
    red[tid] = vp; __syncthreads();
    for (int s = 128; s > 0; s >>= 1) { if (tid < s) red[tid] += red[tid + s]; __syncthreads(); }
    float inv = 1.0f / sqrtf(red[0] * (1.0f / 768.0f) + 1e-5f);
    __syncthreads();
#pragma unroll
    for (int p = 0; p < 3; ++p) {
        int i = tid + 256 * p;
        xln[b * DIM + i] = (xb[i] - mean) * inv * hw[i] + hb[i];
    }
}

// ---------------------------------------------------------------------------
// Head stage 2: h1 = xln @ hw1 + hb1. Grid (BATCH, 12), 256 thr.
// ---------------------------------------------------------------------------
__global__ __launch_bounds__(256)
void head_mm1(const float* __restrict__ xln, const float* __restrict__ w1,
              const float* __restrict__ b1, float* __restrict__ h1) {
    __shared__ float xs[768];
    __shared__ float red[4][64];
    const int b = blockIdx.x, nc = blockIdx.y, tid = threadIdx.x;
    const int nl = tid & 63, q = tid >> 6;       // col-local, k-quarter
#pragma unroll
    for (int p = 0; p < 3; ++p) xs[tid + 256 * p] = xln[b * DIM + tid + 256 * p];
    __syncthreads();
    const int n = nc * 64 + nl;
    float a = 0.f;
    const float* wp = w1 + (size_t)(q * 192) * DIM + n;
#pragma unroll 8
    for (int k = 0; k < 192; ++k) a += xs[q * 192 + k] * wp[(size_t)k * DIM];
    red[q][nl] = a;
    __syncthreads();
    if (q == 0) h1[b * DIM + n] = red[0][nl] + red[1][nl] + red[2][nl] + red[3][nl] + b1[n];
}

// ---------------------------------------------------------------------------
// Head stage 3: out = h1 @ hw2 + hb2. 16 blocks x 256 thr, 2 outputs each.
// ---------------------------------------------------------------------------
__global__ __launch_bounds__(256)
void head_mm2(const float* __restrict__ h1, const float* __restrict__ w2,
              const float* __restrict__ b2, float* __restrict__ out) {
    __shared__ float red[256];
    const int b = blockIdx.x, tid = threadIdx.x;
    float p0 = 0.f, p1 = 0.f;
    for (int k = tid; k < 768; k += 256) {
        float hv = h1[b * DIM + k];
        p0 += hv * w2[k * 2]; p1 += hv * w2[k * 2 + 1];
    }
    red[tid] = p0; __syncthreads();
    for (int s = 128; s > 0; s >>= 1) { if (tid < s) red[tid] += red[tid + s]; __syncthreads(); }
    if (tid == 0) out[b * 2 + 0] = red[0] + b2[0];
    __syncthreads();
    red[tid] = p1; __syncthreads();
    for (int s = 128; s > 0; s >>= 1) { if (tid < s) red[tid] += red[tid + s]; __syncthreads(); }
    if (tid == 0) out[b * 2 + 1] = red[0] + b2[1];
}

// ---------------------------------------------------------------------------
extern "C" void kernel_launch(void* const* d_in, const int* in_sizes, int n_in,
                              void* d_out, int out_size, void* d_ws, size_t ws_size,
                              hipStream_t stream) {
    (void)in_sizes; (void)n_in; (void)out_size; (void)ws_size;
    const float* feat  = (const float*)d_in[0];
    const float* times = (const float*)d_in[1];
    const float* emb_w = (const float*)d_in[2];
    const float* emb_b = (const float*)d_in[3];
    const float* ln1_w = (const float*)d_in[4];
    const float* ln1_b = (const float*)d_in[5];
    const float* w_qkv = (const float*)d_in[6];
    const float* w_o   = (const float*)d_in[7];
    const float* b_o   = (const float*)d_in[8];
    const float* ln2_w = (const float*)d_in[9];
    const float* ln2_b = (const float*)d_in[10];
    const float* w1    = (const float*)d_in[11];
    const float* b1    = (const float*)d_in[12];
    const float* w2    = (const float*)d_in[13];
    const float* b2    = (const float*)d_in[14];
    const float* hln_w = (const float*)d_in[15];
    const float* hln_b = (const float*)d_in[16];
    const float* hw1   = (const float*)d_in[17];
    const float* hb1   = (const float*)d_in[18];
    const float* hw2   = (const float*)d_in[19];
    const float* hb2   = (const float*)d_in[20];
    float* out = (float*)d_out;

    char* ws = (char*)d_ws;
    size_t off = 0;
    auto alloc = [&](size_t bytes) {
        char* p = ws + off; off += (bytes + 255) & ~(size_t)255; return p;
    };
    short* embWT = (short*)alloc((size_t)FDIM * DIM * 2);          // [DIM][FDIM]
    short* wqkvT = (short*)alloc((size_t)NLAYER * DIM * QKVN * 2); // [L][QKVN][DIM]
    short* woT   = (short*)alloc((size_t)NLAYER * DIM * DIM * 2);  // [L][DIM][DIM]
    short* w1T   = (short*)alloc((size_t)NLAYER * DIM * DMLP * 2); // [L][DMLP][DIM]
    short* w2T   = (short*)alloc((size_t)NLAYER * DMLP * DIM * 2); // [L][DIM][DMLP]
    float* x     = (float*)alloc((size_t)TOK * DIM * 4);
    short* xn    = (short*)alloc((size_t)TOK * DIM * 2);
    short* qkvB  = (short*)alloc((size_t)TOK * QKVN * 2);
    short* oB    = (short*)alloc((size_t)TOK * DIM * 2);
    short* hB    = (short*)alloc((size_t)TOK * DMLP * 2);          // 50 MB
    float* pooled= (float*)alloc((size_t)BATCH * DIM * 4);
    float* xlnH  = (float*)alloc((size_t)BATCH * DIM * 4);
    float* h1H   = (float*)alloc((size_t)BATCH * DIM * 4);
    // featB aliases hB: featB is dead after the embedding GEMM; hB's first
    // write (layer-0 mlp1) is strictly later. Saves 16 MB of workspace.
    short* featB = hB;   // TOK*FDIM*2 = 32 MB <= hB's 50 MB

    // feat: plain convert (already K-contiguous as GEMM A operand)
    {
        int n4 = (int)((size_t)TOK * FDIM / 4);
        cvt_f32_bf16<<<2048, 256, 0, stream>>>(feat, featB, n4);
    }
    // weights: transpose + convert -> [N][K] bf16
    transpose_cvt<<<dim3(FDIM / 64, DIM / 64, 1), 256, 0, stream>>>(emb_w, embWT, FDIM, DIM);
    transpose_cvt<<<dim3(DIM / 64, QKVN / 64, NLAYER), 256, 0, stream>>>(w_qkv, wqkvT, DIM, QKVN);
    transpose_cvt<<<dim3(DIM / 64, DIM / 64, NLAYER), 256, 0, stream>>>(w_o, woT, DIM, DIM);
    transpose_cvt<<<dim3(DIM / 64, DMLP / 64, NLAYER), 256, 0, stream>>>(w1, w1T, DIM, DMLP);
    transpose_cvt<<<dim3(DMLP / 64, DIM / 64, NLAYER), 256, 0, stream>>>(w2, w2T, DMLP, DIM);

    // embedding: x = feat @ emb_w + emb_b  (TM=64: 768 blocks = 3/CU)
    gemm_bt<0, 64><<<dim3(TOK / 64, DIM / 128), 256, 0, stream>>>(
        featB, embWT, emb_b, nullptr, x, nullptr, TOK, DIM, FDIM);

    for (int l = 0; l < NLAYER; ++l) {
        ln_rows<<<TOK / 4, 256, 0, stream>>>(x, ln1_w + l * DIM, ln1_b + l * DIM, xn);
        gemm_bt<1, 128><<<dim3(TOK / 128, QKVN / 128), 256, 0, stream>>>(
            xn, wqkvT + (size_t)l * DIM * QKVN, nullptr, nullptr, nullptr, qkvB, TOK, QKVN, DIM);
        attn_fused<<<dim3(BATCH * NH, SEQ / 64), 256, 0, stream>>>(qkvB, times, oB);
        gemm_bt<2, 64><<<dim3(TOK / 64, DIM / 128), 256, 0, stream>>>(
            oB, woT + (size_t)l * DIM * DIM, b_o + l * DIM, x, x, nullptr, TOK, DIM, DIM);
        ln_rows<<<TOK / 4, 256, 0, stream>>>(x, ln2_w + l * DIM, ln2_b + l * DIM, xn);
        gemm_bt<3, 128><<<dim3(TOK / 128, DMLP / 128), 256, 0, stream>>>(
            xn, w1T + (size_t)l * DIM * DMLP, b1 + l * DMLP, nullptr, nullptr, hB, TOK, DMLP, DIM);
        gemm_bt<2, 64><<<dim3(TOK / 64, DIM / 128), 256, 0, stream>>>(
            hB, w2T + (size_t)l * DMLP * DIM, b2 + l * DIM, x, x, nullptr, TOK, DIM, DMLP);
    }

    pool_kernel<<<dim3(BATCH, 3), 256, 0, stream>>>(x, pooled);
    head_ln<<<BATCH, 256, 0, stream>>>(pooled, hln_w, hln_b, xlnH);
    head_mm1<<<dim3(BATCH, 12), 256, 0, stream>>>(xlnH, hw1, hb1, h1H);
    head_mm2<<<BATCH, 256, 0, stream>>>(h1H, hw2, hb2, out);
}